// Round 8
// baseline (71.495 us; speedup 1.0000x reference)
//
#include <hip/hip_runtime.h>

using short8 = __attribute__((ext_vector_type(8))) short;
using f32x4  = __attribute__((ext_vector_type(4))) float;
using u32x4  = __attribute__((ext_vector_type(4))) unsigned int;

#define NC 256
#define NW 64
#define ND 21
#define HW 3072              /* 48*64, per-channel stride in floats */
#define H2 24

static const size_t WS_F2   = (size_t)384 * 32 * 1024;   /* f2 blobs only  */
static const size_t WS_FULL = (size_t)768 * 32 * 1024;   /* f2 + f1 blobs  */

__device__ __forceinline__ int imax(int a, int b) { return a > b ? a : b; }
__device__ __forceinline__ int imin(int a, int b) { return a < b ? a : b; }

__device__ __forceinline__ unsigned int cvtpk(float a, float b) {
    unsigned int r;
    asm("v_cvt_pk_bf16_f32 %0, %1, %2" : "=v"(r) : "v"(a), "v"(b));
    return r;
}

// byte offset into a [64 rows][256 ch] bf16 tile, XOR-swizzled (verified R1-R6)
__device__ __forceinline__ unsigned int swz_off(int row, int cb) {
    return (row << 9) + ((cb << 1) ^ (((row >> 1) & 7) << 4));
}

// blob base: blobs are 16384 ushorts = 32 KB each.  R7 BUG: computed this on a
// char* with <<14 (16 KB stride) -> read wrong blobs.  Keep arithmetic on the
// ushort* (<<14 ushorts) and cast afterwards.
__device__ __forceinline__ const char* blob_base(const unsigned short* ws, int id) {
    return reinterpret_cast<const char*>(ws + ((size_t)id << 14));
}

// barrier draining LDS ops only — global loads/stores stay in flight
#define BARRIER() asm volatile("s_waitcnt lgkmcnt(0)\n\ts_barrier" ::: "memory")

struct Stage { float2 v[16]; };   // one f32 row slice: 128 B/thread

__device__ __forceinline__ void stage_issue(Stage& st, const float* rowbase, int xp, int cg) {
    const float* s = rowbase + 2 * xp;
    #pragma unroll
    for (int cc = 0; cc < 2; ++cc)
        #pragma unroll
        for (int e = 0; e < 4; ++e) {
            int c = cc * 128 + cg * 8 + 2 * e;
            st.v[cc * 8 + 2 * e    ] = *reinterpret_cast<const float2*>(s + (size_t)c * HW);
            st.v[cc * 8 + 2 * e + 1] = *reinterpret_cast<const float2*>(s + (size_t)(c + 1) * HW);
        }
}

__device__ __forceinline__ void stage_pack(const Stage& st, int cc, u32x4& p0, u32x4& p1) {
    #pragma unroll
    for (int e = 0; e < 4; ++e) {
        float2 va = st.v[cc * 8 + 2 * e];
        float2 vb = st.v[cc * 8 + 2 * e + 1];
        p0[e] = cvtpk(va.x, vb.x);
        p1[e] = cvtpk(va.y, vb.y);
    }
}

__device__ __forceinline__ void stage_commit_lds(const Stage& st, unsigned short* lds, int xp, int cg) {
    #pragma unroll
    for (int cc = 0; cc < 2; ++cc) {
        int c0 = cc * 128 + cg * 8;
        u32x4 p0, p1;
        stage_pack(st, cc, p0, p1);
        *reinterpret_cast<u32x4*>(reinterpret_cast<char*>(lds) + swz_off(2 * xp,     c0)) = p0;
        *reinterpret_cast<u32x4*>(reinterpret_cast<char*>(lds) + swz_off(2 * xp + 1, c0)) = p1;
    }
}

__device__ __forceinline__ void stage_commit_glob(const Stage& st, unsigned short* blob, int xp, int cg) {
    #pragma unroll
    for (int cc = 0; cc < 2; ++cc) {
        int c0 = cc * 128 + cg * 8;
        u32x4 p0, p1;
        stage_pack(st, cc, p0, p1);
        *reinterpret_cast<u32x4*>(reinterpret_cast<char*>(blob) + swz_off(2 * xp,     c0)) = p0;
        *reinterpret_cast<u32x4*>(reinterpret_cast<char*>(blob) + swz_off(2 * xp + 1, c0)) = p1;
    }
}

// ---- pre-pass: f32 [c][x] row -> bf16 blob [x][c] swizzled (32 KB each) ----
// XCD-aligned: blob (b*48+y) is produced on XCD b (bid%8==b), same XCD as its
// consumers in the main kernel -> blob reads are local-L2 hits.
// grid 384: f2 blobs 0..383.  grid 768: + f1 blobs 384..767.
__global__ __launch_bounds__(512, 4) void prep_kernel(const float* __restrict__ f1,
                                                      const float* __restrict__ f2,
                                                      unsigned short* __restrict__ ws) {
    int bid = blockIdx.x;
    int xcd = bid & 7;
    int m   = bid >> 3;            // [0,96)
    const float* src;
    int rid, blob_id;
    if (m < 48) { rid = xcd * 48 + m;        blob_id = rid;       src = f2; }
    else        { rid = xcd * 48 + (m - 48); blob_id = 384 + rid; src = f1; }
    int b = rid / 48, y = rid - b * 48;
    const float* row = src + (size_t)b * NC * HW + (size_t)y * NW;
    unsigned short* blob = ws + ((size_t)blob_id << 14);
    int tid = threadIdx.x, xp = tid & 31, cg = tid >> 5;
    Stage st;
    stage_issue(st, row, xp, cg);
    stage_commit_glob(st, blob, xp, cg);
}

// ---- main kernel v4: fragments DIRECT from global blobs; LDS = Sl only ----
// Per iteration: MFMA (prefetched bfrag) -> S to LDS -> barrier -> gather ->
// barrier. No B staging through LDS (R3-R6's ~110 KB/iter LDS round trip).
__global__ __launch_bounds__(512, 6) void corr_main4(const unsigned short* __restrict__ ws,
                                                     float* __restrict__ out) {
    __shared__ float Sl[64 * 32];                         // 8 KB, additive-swizzled

    int bid = blockIdx.x;
    // bijective XCD swizzle: 768 = 8*96; XCD k serves batch b=k only
    int swz = (bid & 7) * 96 + (bid >> 3);
    int hf  = swz & 1;
    int uy  = (swz >> 1) % 24;
    int g   = swz / 48;            // b*2 + py
    int py  = g & 1, b = g >> 1;
    int y   = 2 * uy + py;

    int tid = threadIdx.x, lane = tid & 63, w = tid >> 6;
    int px = w & 1, m0 = ((w >> 1) & 1) * 16, n0 = ((w >> 2) & 1) * 16;
    int l15 = lane & 15, g4 = lane >> 4;

    float* outb = out + (size_t)b * 441 * HW + (size_t)y * NW;   // + d*HW + x

    int ilo_h = hf ? 11 : 0, ihi_h = hf ? 20 : 10;
    int ilo   = imax(ilo_h, 10 - uy);
    int ihi   = imin(ihi_h, 33 - uy);

    // zero-fill output rows whose displaced source row is out of bounds
    for (int i = ilo_h; i <= ihi_h; ++i) {
        if (i >= ilo && i <= ihi) continue;
        for (int t = tid; t < ND * 64; t += 512) {
            int j = t >> 6, x = t & 63;
            outb[(size_t)(i * ND + j) * HW + x] = 0.f;
        }
    }
    if (ilo > ihi) return;

    // ---- A fragments direct from f1 blob (one-time, L2-local) ----
    const char* ablob = blob_base(ws, 384 + b * 48 + y);
    int arow = 2 * (m0 + l15) + px;
    short8 afrag[8];
    #pragma unroll
    for (int kk = 0; kk < 8; ++kk)
        afrag[kk] = *reinterpret_cast<const short8*>(ablob + swz_off(arow, kk * 32 + g4 * 8));

    int brow = 2 * (n0 + l15) + px;
    int srow = 2 * (m0 + g4 * 4) + px;           // + 2*rr
    int scol = n0 + l15;

    // ---- gather precompute (iteration-invariant) ----
    int x  = tid & 63;
    int j0 = tid >> 6;                            // slots j0, j0+8, j0+16
    unsigned lidx[3]; int joff[3]; bool valid[3]; bool jok[3];
    #pragma unroll
    for (int s = 0; s < 3; ++s) {
        int j  = j0 + 8 * s;
        jok[s] = (j < ND);
        int vx = (x >> 1) + j - 10;
        valid[s] = ((unsigned)vx < 32u);
        lidx[s]  = (x << 5) | ((vx + x) & 31);
        joff[s]  = j * HW + x;
    }

    auto loadB = [&](short8* bf, int i) {
        const char* bb = blob_base(ws, b * 48 + 2 * (uy + i - 10) + py);
        #pragma unroll
        for (int kk = 0; kk < 8; ++kk)
            bf[kk] = *reinterpret_cast<const short8*>(bb + swz_off(brow, kk * 32 + g4 * 8));
    };

    short8 bf[8];
    loadB(bf, ilo);                               // prologue prefetch

    for (int i = ilo; i <= ihi; ++i) {
        f32x4 acc = {0.f, 0.f, 0.f, 0.f};
        #pragma unroll
        for (int kk = 0; kk < 8; ++kk)
            acc = __builtin_amdgcn_mfma_f32_16x16x32_bf16(afrag[kk], bf[kk], acc, 0, 0, 0);
        if (i < ihi) loadB(bf, i + 1);            // in flight across S-write+barrier+gather

        // C/D: col = lane&15 -> vx, row = g4*4 + rr -> ux (verified R1-R6)
        // S swizzle: idx = row*32 + ((col+row)&31) -> 2-way (free) both sides
        #pragma unroll
        for (int rr = 0; rr < 4; ++rr) {
            int row = srow + 2 * rr;
            Sl[(row << 5) | ((scol + row) & 31)] = acc[rr] * (1.f / 256.f);
        }
        BARRIER();   // S ready

        float* oi = outb + (size_t)i * (ND * HW);
        #pragma unroll
        for (int s = 0; s < 3; ++s) {
            if (!jok[s]) continue;
            float v = valid[s] ? Sl[lidx[s]] : 0.f;
            oi[joff[s]] = v;
        }
        BARRIER();   // gather reads retired; Sl overwritable
    }
}

// ---- middle tier (f2 blobs only): A staged from f32, B direct from blobs ----
__global__ __launch_bounds__(512, 6) void corr_main3f(const float* __restrict__ f1,
                                                      const unsigned short* __restrict__ ws,
                                                      float* __restrict__ out) {
    __shared__ __align__(16) unsigned short buf[16384];
    __shared__ float Sl[64 * 32];

    int bid = blockIdx.x;
    int swz = (bid & 7) * 96 + (bid >> 3);
    int hf  = swz & 1;
    int uy  = (swz >> 1) % 24;
    int g   = swz / 48;
    int py  = g & 1, b = g >> 1;
    int y   = 2 * uy + py;

    int tid = threadIdx.x, lane = tid & 63, w = tid >> 6;
    int px = w & 1, m0 = ((w >> 1) & 1) * 16, n0 = ((w >> 2) & 1) * 16;
    int l15 = lane & 15, g4 = lane >> 4;

    float* outb = out + (size_t)b * 441 * HW + (size_t)y * NW;

    int ilo_h = hf ? 11 : 0, ihi_h = hf ? 20 : 10;
    int ilo   = imax(ilo_h, 10 - uy);
    int ihi   = imin(ihi_h, 33 - uy);

    for (int i = ilo_h; i <= ihi_h; ++i) {
        if (i >= ilo && i <= ihi) continue;
        for (int t = tid; t < ND * 64; t += 512) {
            int j = t >> 6, x = t & 63;
            outb[(size_t)(i * ND + j) * HW + x] = 0.f;
        }
    }
    if (ilo > ihi) return;

    Stage s;
    stage_issue(s, f1 + (size_t)b * NC * HW + (size_t)y * NW, tid & 31, tid >> 5);
    stage_commit_lds(s, buf, tid & 31, tid >> 5);
    BARRIER();
    short8 afrag[8];
    int arow = 2 * (m0 + l15) + px;
    #pragma unroll
    for (int kk = 0; kk < 8; ++kk)
        afrag[kk] = *reinterpret_cast<const short8*>(
            reinterpret_cast<const char*>(buf) + swz_off(arow, kk * 32 + g4 * 8));
    BARRIER();

    int brow = 2 * (n0 + l15) + px;
    int srow = 2 * (m0 + g4 * 4) + px;
    int scol = n0 + l15;

    auto loadB = [&](short8* bf, int i) {
        const char* bb = blob_base(ws, b * 48 + 2 * (uy + i - 10) + py);
        #pragma unroll
        for (int kk = 0; kk < 8; ++kk)
            bf[kk] = *reinterpret_cast<const short8*>(bb + swz_off(brow, kk * 32 + g4 * 8));
    };

    short8 bf[8];
    loadB(bf, ilo);

    for (int i = ilo; i <= ihi; ++i) {
        f32x4 acc = {0.f, 0.f, 0.f, 0.f};
        #pragma unroll
        for (int kk = 0; kk < 8; ++kk)
            acc = __builtin_amdgcn_mfma_f32_16x16x32_bf16(afrag[kk], bf[kk], acc, 0, 0, 0);
        if (i < ihi) loadB(bf, i + 1);
        #pragma unroll
        for (int rr = 0; rr < 4; ++rr) {
            int row = srow + 2 * rr;
            Sl[(row << 5) | ((scol + row) & 31)] = acc[rr] * (1.f / 256.f);
        }
        BARRIER();
        for (int t = tid; t < ND * 64; t += 512) {
            int j = t >> 6, x = t & 63;
            int vx = (x >> 1) + j - 10;
            float v = ((unsigned)vx < 32u) ? Sl[(x << 5) | ((vx + x) & 31)] : 0.f;
            outb[(size_t)(i * ND + j) * HW + x] = v;
        }
        BARRIER();
    }
}

// ---- fallback (round-1 structure, known good, no workspace) ----
__global__ __launch_bounds__(512, 4) void corr_fallback(const float* __restrict__ f1,
                                                        const float* __restrict__ f2,
                                                        float* __restrict__ out) {
    __shared__ __align__(16) unsigned short Alds[64 * 256];
    __shared__ __align__(16) unsigned short Blds[64 * 256];
    __shared__ float Slds[64][33];

    int bid = blockIdx.x;
    int swz = (bid & 7) * 48 + (bid >> 3);
    int uy = swz % 24;
    int g  = swz / 24;
    int py = g & 1;
    int b  = g >> 1;
    int y  = 2 * uy + py;

    int tid = threadIdx.x, lane = tid & 63, w = tid >> 6;
    int xp = tid & 31, cg = tid >> 5;

    const float* f1row  = f1 + (size_t)b * NC * HW + (size_t)y * NW;
    const float* f2base = f2 + (size_t)b * NC * HW;
    float* outb = out + (size_t)b * 441 * HW + (size_t)y * NW;

    for (int i = 0; i < ND; ++i) {
        int vy = uy + i - 10;
        if (vy >= 0 && vy < H2) continue;
        for (int t = tid; t < ND * 64; t += 512) {
            int j = t >> 6, x = t & 63;
            outb[(size_t)(i * ND + j) * HW + x] = 0.f;
        }
    }

    Stage st;
    stage_issue(st, f1row, xp, cg);
    stage_commit_lds(st, Alds, xp, cg);
    __syncthreads();

    int px  = w & 1;
    int m0  = ((w >> 1) & 1) * 16;
    int n0  = ((w >> 2) & 1) * 16;
    int l15 = lane & 15;
    int kgr = (lane >> 4) * 8;

    short8 afrag[8];
    int arow = 2 * (m0 + l15) + px;
    #pragma unroll
    for (int kk = 0; kk < 8; ++kk)
        afrag[kk] = *reinterpret_cast<const short8*>(
            reinterpret_cast<const char*>(Alds) + swz_off(arow, kk * 32 + kgr));

    int brow = 2 * (n0 + l15) + px;
    int srow = 2 * (m0 + (lane >> 4) * 4) + px;
    int scol = n0 + l15;

    for (int vy = uy - 10; vy <= uy + 10; ++vy) {
        if (vy < 0 || vy >= H2) continue;
        int i  = vy - uy + 10;
        int y2 = 2 * vy + py;
        __syncthreads();
        stage_issue(st, f2base + (size_t)y2 * NW, xp, cg);
        stage_commit_lds(st, Blds, xp, cg);
        __syncthreads();

        f32x4 acc = {0.f, 0.f, 0.f, 0.f};
        #pragma unroll
        for (int kk = 0; kk < 8; ++kk) {
            short8 bfrag = *reinterpret_cast<const short8*>(
                reinterpret_cast<const char*>(Blds) + swz_off(brow, kk * 32 + kgr));
            acc = __builtin_amdgcn_mfma_f32_16x16x32_bf16(afrag[kk], bfrag, acc, 0, 0, 0);
        }
        #pragma unroll
        for (int r = 0; r < 4; ++r)
            Slds[srow + 2 * r][scol] = acc[r] * (1.f / 256.f);
        __syncthreads();

        for (int t = tid; t < ND * 64; t += 512) {
            int j = t >> 6, x = t & 63;
            int vx = (x >> 1) + j - 10;
            float v = ((unsigned)vx < 32u) ? Slds[x][vx] : 0.f;
            outb[(size_t)(i * ND + j) * HW + x] = v;
        }
    }
}

extern "C" void kernel_launch(void* const* d_in, const int* in_sizes, int n_in,
                              void* d_out, int out_size, void* d_ws, size_t ws_size,
                              hipStream_t stream) {
    const float* in1 = (const float*)d_in[0];
    const float* in2 = (const float*)d_in[1];
    float* o = (float*)d_out;
    if (ws_size >= WS_FULL) {
        hipLaunchKernelGGL(prep_kernel, dim3(768), dim3(512), 0, stream, in1, in2, (unsigned short*)d_ws);
        hipLaunchKernelGGL(corr_main4, dim3(768), dim3(512), 0, stream,
                           (const unsigned short*)d_ws, o);
    } else if (ws_size >= WS_F2) {
        hipLaunchKernelGGL(prep_kernel, dim3(384), dim3(512), 0, stream, in1, in2, (unsigned short*)d_ws);
        hipLaunchKernelGGL(corr_main3f, dim3(768), dim3(512), 0, stream,
                           in1, (const unsigned short*)d_ws, o);
    } else {
        hipLaunchKernelGGL(corr_fallback, dim3(384), dim3(512), 0, stream, in1, in2, o);
    }
}

// Round 9
// 47.905 us; speedup vs baseline: 1.4924x; 1.4924x over previous
//
#include <hip/hip_runtime.h>

using short8 = __attribute__((ext_vector_type(8))) short;
using f32x4  = __attribute__((ext_vector_type(4))) float;
using u32x4  = __attribute__((ext_vector_type(4))) unsigned int;

#define NC 256
#define NW 64
#define ND 21
#define HW 3072              /* 48*64, per-channel stride in floats */
#define H2 24

static const size_t WS_F2   = (size_t)384 * 32 * 1024;   /* f2 blobs only  */
static const size_t WS_FULL = (size_t)768 * 32 * 1024;   /* f2 + f1 blobs  */

__device__ __forceinline__ int imax(int a, int b) { return a > b ? a : b; }
__device__ __forceinline__ int imin(int a, int b) { return a < b ? a : b; }

__device__ __forceinline__ unsigned int cvtpk(float a, float b) {
    unsigned int r;
    asm("v_cvt_pk_bf16_f32 %0, %1, %2" : "=v"(r) : "v"(a), "v"(b));
    return r;
}

// byte offset into a [64 rows][256 ch] bf16 tile, XOR-swizzled (verified R1-R8)
__device__ __forceinline__ unsigned int swz_off(int row, int cb) {
    return (row << 9) + ((cb << 1) ^ (((row >> 1) & 7) << 4));
}

// blob base: blobs are 16384 ushorts = 32 KB each.  (R7 bug: did <<14 on a
// char* = 16 KB stride.  Arithmetic stays on the ushort*, cast afterwards.)
__device__ __forceinline__ const char* blob_base(const unsigned short* ws, int id) {
    return reinterpret_cast<const char*>(ws + ((size_t)id << 14));
}

// barrier draining LDS ops only — global loads/stores stay in flight
#define BARRIER() asm volatile("s_waitcnt lgkmcnt(0)\n\ts_barrier" ::: "memory")

struct Stage { float2 v[16]; };   // one f32 row slice: 128 B/thread

__device__ __forceinline__ void stage_issue(Stage& st, const float* rowbase, int xp, int cg) {
    const float* s = rowbase + 2 * xp;
    #pragma unroll
    for (int cc = 0; cc < 2; ++cc)
        #pragma unroll
        for (int e = 0; e < 4; ++e) {
            int c = cc * 128 + cg * 8 + 2 * e;
            st.v[cc * 8 + 2 * e    ] = *reinterpret_cast<const float2*>(s + (size_t)c * HW);
            st.v[cc * 8 + 2 * e + 1] = *reinterpret_cast<const float2*>(s + (size_t)(c + 1) * HW);
        }
}

__device__ __forceinline__ void stage_pack(const Stage& st, int cc, u32x4& p0, u32x4& p1) {
    #pragma unroll
    for (int e = 0; e < 4; ++e) {
        float2 va = st.v[cc * 8 + 2 * e];
        float2 vb = st.v[cc * 8 + 2 * e + 1];
        p0[e] = cvtpk(va.x, vb.x);
        p1[e] = cvtpk(va.y, vb.y);
    }
}

__device__ __forceinline__ void stage_commit_lds(const Stage& st, unsigned short* lds, int xp, int cg) {
    #pragma unroll
    for (int cc = 0; cc < 2; ++cc) {
        int c0 = cc * 128 + cg * 8;
        u32x4 p0, p1;
        stage_pack(st, cc, p0, p1);
        *reinterpret_cast<u32x4*>(reinterpret_cast<char*>(lds) + swz_off(2 * xp,     c0)) = p0;
        *reinterpret_cast<u32x4*>(reinterpret_cast<char*>(lds) + swz_off(2 * xp + 1, c0)) = p1;
    }
}

__device__ __forceinline__ void stage_commit_glob(const Stage& st, unsigned short* blob, int xp, int cg) {
    #pragma unroll
    for (int cc = 0; cc < 2; ++cc) {
        int c0 = cc * 128 + cg * 8;
        u32x4 p0, p1;
        stage_pack(st, cc, p0, p1);
        *reinterpret_cast<u32x4*>(reinterpret_cast<char*>(blob) + swz_off(2 * xp,     c0)) = p0;
        *reinterpret_cast<u32x4*>(reinterpret_cast<char*>(blob) + swz_off(2 * xp + 1, c0)) = p1;
    }
}

// ---- pre-pass: f32 [c][x] row -> bf16 blob [x][c] swizzled (32 KB each) ----
// XCD-aligned: blob (b*48+y) is produced on XCD b (bid%8==b), same XCD as its
// consumers in the main kernel -> blob reads are local-L2 hits.
__global__ __launch_bounds__(512, 4) void prep_kernel(const float* __restrict__ f1,
                                                      const float* __restrict__ f2,
                                                      unsigned short* __restrict__ ws) {
    int bid = blockIdx.x;
    int xcd = bid & 7;
    int m   = bid >> 3;            // [0,96)
    const float* src;
    int rid, blob_id;
    if (m < 48) { rid = xcd * 48 + m;        blob_id = rid;       src = f2; }
    else        { rid = xcd * 48 + (m - 48); blob_id = 384 + rid; src = f1; }
    int b = rid / 48, y = rid - b * 48;
    const float* row = src + (size_t)b * NC * HW + (size_t)y * NW;
    unsigned short* blob = ws + ((size_t)blob_id << 14);
    int tid = threadIdx.x, xp = tid & 31, cg = tid >> 5;
    Stage st;
    stage_issue(st, row, xp, cg);
    stage_commit_glob(st, blob, xp, cg);
}

// ---- main kernel v4: fragments DIRECT from global blobs; LDS = Sl[2] only ----
// (512,4): R5/R8 evidence — 2nd launch_bounds arg >=6 makes the allocator
// spill afrag/bf to scratch (VGPR 32/40, +28 MB scratch writes) and destroys
// the B prefetch pipeline.  At (512,4) the ~80 live regs fit -> ~6 waves/SIMD.
__global__ __launch_bounds__(512, 4) void corr_main4(const unsigned short* __restrict__ ws,
                                                     float* __restrict__ out) {
    __shared__ float Sl[2][64 * 32];                      // 2 x 8 KB, additive-swizzled

    int bid = blockIdx.x;
    // bijective XCD swizzle: 768 = 8*96; XCD k serves batch b=k only
    int swz = (bid & 7) * 96 + (bid >> 3);
    int hf  = swz & 1;
    int uy  = (swz >> 1) % 24;
    int g   = swz / 48;            // b*2 + py
    int py  = g & 1, b = g >> 1;
    int y   = 2 * uy + py;

    int tid = threadIdx.x, lane = tid & 63, w = tid >> 6;
    int px = w & 1, m0 = ((w >> 1) & 1) * 16, n0 = ((w >> 2) & 1) * 16;
    int l15 = lane & 15, g4 = lane >> 4;

    float* outb = out + (size_t)b * 441 * HW + (size_t)y * NW;   // + d*HW + x

    int ilo_h = hf ? 11 : 0, ihi_h = hf ? 20 : 10;
    int ilo   = imax(ilo_h, 10 - uy);
    int ihi   = imin(ihi_h, 33 - uy);

    // zero-fill output rows whose displaced source row is out of bounds
    for (int i = ilo_h; i <= ihi_h; ++i) {
        if (i >= ilo && i <= ihi) continue;
        for (int t = tid; t < ND * 64; t += 512) {
            int j = t >> 6, x = t & 63;
            outb[(size_t)(i * ND + j) * HW + x] = 0.f;
        }
    }
    if (ilo > ihi) return;

    // ---- A fragments direct from f1 blob (one-time, L2-local) ----
    const char* ablob = blob_base(ws, 384 + b * 48 + y);
    int arow = 2 * (m0 + l15) + px;
    short8 afrag[8];
    #pragma unroll
    for (int kk = 0; kk < 8; ++kk)
        afrag[kk] = *reinterpret_cast<const short8*>(ablob + swz_off(arow, kk * 32 + g4 * 8));

    int brow = 2 * (n0 + l15) + px;
    int srow = 2 * (m0 + g4 * 4) + px;           // + 2*rr
    int scol = n0 + l15;

    // ---- gather precompute (iteration-invariant) ----
    int x  = tid & 63;
    int j0 = tid >> 6;                            // slots j0, j0+8, j0+16
    unsigned lidx[3]; int joff[3]; bool valid[3]; bool jok[3];
    #pragma unroll
    for (int s = 0; s < 3; ++s) {
        int j  = j0 + 8 * s;
        jok[s] = (j < ND);
        int vx = (x >> 1) + j - 10;
        valid[s] = ((unsigned)vx < 32u);
        lidx[s]  = (x << 5) | ((vx + x) & 31);
        joff[s]  = j * HW + x;
    }

    auto loadB = [&](short8* bf, int i) {
        const char* bb = blob_base(ws, b * 48 + 2 * (uy + i - 10) + py);
        #pragma unroll
        for (int kk = 0; kk < 8; ++kk)
            bf[kk] = *reinterpret_cast<const short8*>(bb + swz_off(brow, kk * 32 + g4 * 8));
    };

    short8 bf[8];
    loadB(bf, ilo);                               // prologue prefetch

    for (int i = ilo; i <= ihi; ++i) {
        float* S = Sl[(i - ilo) & 1];             // double-buffer: 1 barrier/iter.
        // gather of buffer k is fenced from the k+2 overwrite by the k+1 barrier.
        f32x4 acc = {0.f, 0.f, 0.f, 0.f};
        #pragma unroll
        for (int kk = 0; kk < 8; ++kk)
            acc = __builtin_amdgcn_mfma_f32_16x16x32_bf16(afrag[kk], bf[kk], acc, 0, 0, 0);
        if (i < ihi) loadB(bf, i + 1);            // in flight across S-write+barrier+gather

        // C/D: col = lane&15 -> vx, row = g4*4 + rr -> ux (verified R1-R8)
        // S swizzle: idx = row*32 + ((col+row)&31) -> 2-way (free) both sides
        #pragma unroll
        for (int rr = 0; rr < 4; ++rr) {
            int row = srow + 2 * rr;
            S[(row << 5) | ((scol + row) & 31)] = acc[rr] * (1.f / 256.f);
        }
        BARRIER();   // S ready (also fences prev-prev buffer reuse)

        float* oi = outb + (size_t)i * (ND * HW);
        #pragma unroll
        for (int s = 0; s < 3; ++s) {
            if (!jok[s]) continue;
            float v = valid[s] ? S[lidx[s]] : 0.f;
            oi[joff[s]] = v;
        }
    }
}

// ---- middle tier (f2 blobs only): A staged from f32, B direct from blobs ----
__global__ __launch_bounds__(512, 4) void corr_main3f(const float* __restrict__ f1,
                                                      const unsigned short* __restrict__ ws,
                                                      float* __restrict__ out) {
    __shared__ __align__(16) unsigned short buf[16384];
    __shared__ float Sl[2][64 * 32];

    int bid = blockIdx.x;
    int swz = (bid & 7) * 96 + (bid >> 3);
    int hf  = swz & 1;
    int uy  = (swz >> 1) % 24;
    int g   = swz / 48;
    int py  = g & 1, b = g >> 1;
    int y   = 2 * uy + py;

    int tid = threadIdx.x, lane = tid & 63, w = tid >> 6;
    int px = w & 1, m0 = ((w >> 1) & 1) * 16, n0 = ((w >> 2) & 1) * 16;
    int l15 = lane & 15, g4 = lane >> 4;

    float* outb = out + (size_t)b * 441 * HW + (size_t)y * NW;

    int ilo_h = hf ? 11 : 0, ihi_h = hf ? 20 : 10;
    int ilo   = imax(ilo_h, 10 - uy);
    int ihi   = imin(ihi_h, 33 - uy);

    for (int i = ilo_h; i <= ihi_h; ++i) {
        if (i >= ilo && i <= ihi) continue;
        for (int t = tid; t < ND * 64; t += 512) {
            int j = t >> 6, x = t & 63;
            outb[(size_t)(i * ND + j) * HW + x] = 0.f;
        }
    }
    if (ilo > ihi) return;

    Stage s;
    stage_issue(s, f1 + (size_t)b * NC * HW + (size_t)y * NW, tid & 31, tid >> 5);
    stage_commit_lds(s, buf, tid & 31, tid >> 5);
    BARRIER();
    short8 afrag[8];
    int arow = 2 * (m0 + l15) + px;
    #pragma unroll
    for (int kk = 0; kk < 8; ++kk)
        afrag[kk] = *reinterpret_cast<const short8*>(
            reinterpret_cast<const char*>(buf) + swz_off(arow, kk * 32 + g4 * 8));

    int brow = 2 * (n0 + l15) + px;
    int srow = 2 * (m0 + g4 * 4) + px;
    int scol = n0 + l15;

    auto loadB = [&](short8* bf, int i) {
        const char* bb = blob_base(ws, b * 48 + 2 * (uy + i - 10) + py);
        #pragma unroll
        for (int kk = 0; kk < 8; ++kk)
            bf[kk] = *reinterpret_cast<const short8*>(bb + swz_off(brow, kk * 32 + g4 * 8));
    };

    short8 bf[8];
    loadB(bf, ilo);

    for (int i = ilo; i <= ihi; ++i) {
        float* S = Sl[(i - ilo) & 1];
        f32x4 acc = {0.f, 0.f, 0.f, 0.f};
        #pragma unroll
        for (int kk = 0; kk < 8; ++kk)
            acc = __builtin_amdgcn_mfma_f32_16x16x32_bf16(afrag[kk], bf[kk], acc, 0, 0, 0);
        if (i < ihi) loadB(bf, i + 1);
        #pragma unroll
        for (int rr = 0; rr < 4; ++rr) {
            int row = srow + 2 * rr;
            S[(row << 5) | ((scol + row) & 31)] = acc[rr] * (1.f / 256.f);
        }
        BARRIER();
        for (int t = tid; t < ND * 64; t += 512) {
            int j = t >> 6, x = t & 63;
            int vx = (x >> 1) + j - 10;
            float v = ((unsigned)vx < 32u) ? S[(x << 5) | ((vx + x) & 31)] : 0.f;
            outb[(size_t)(i * ND + j) * HW + x] = v;
        }
    }
}

// ---- fallback (round-1 structure, known good, no workspace) ----
__global__ __launch_bounds__(512, 4) void corr_fallback(const float* __restrict__ f1,
                                                        const float* __restrict__ f2,
                                                        float* __restrict__ out) {
    __shared__ __align__(16) unsigned short Alds[64 * 256];
    __shared__ __align__(16) unsigned short Blds[64 * 256];
    __shared__ float Slds[64][33];

    int bid = blockIdx.x;
    int swz = (bid & 7) * 48 + (bid >> 3);
    int uy = swz % 24;
    int g  = swz / 24;
    int py = g & 1;
    int b  = g >> 1;
    int y  = 2 * uy + py;

    int tid = threadIdx.x, lane = tid & 63, w = tid >> 6;
    int xp = tid & 31, cg = tid >> 5;

    const float* f1row  = f1 + (size_t)b * NC * HW + (size_t)y * NW;
    const float* f2base = f2 + (size_t)b * NC * HW;
    float* outb = out + (size_t)b * 441 * HW + (size_t)y * NW;

    for (int i = 0; i < ND; ++i) {
        int vy = uy + i - 10;
        if (vy >= 0 && vy < H2) continue;
        for (int t = tid; t < ND * 64; t += 512) {
            int j = t >> 6, x = t & 63;
            outb[(size_t)(i * ND + j) * HW + x] = 0.f;
        }
    }

    Stage st;
    stage_issue(st, f1row, xp, cg);
    stage_commit_lds(st, Alds, xp, cg);
    __syncthreads();

    int px  = w & 1;
    int m0  = ((w >> 1) & 1) * 16;
    int n0  = ((w >> 2) & 1) * 16;
    int l15 = lane & 15;
    int kgr = (lane >> 4) * 8;

    short8 afrag[8];
    int arow = 2 * (m0 + l15) + px;
    #pragma unroll
    for (int kk = 0; kk < 8; ++kk)
        afrag[kk] = *reinterpret_cast<const short8*>(
            reinterpret_cast<const char*>(Alds) + swz_off(arow, kk * 32 + kgr));

    int brow = 2 * (n0 + l15) + px;
    int srow = 2 * (m0 + (lane >> 4) * 4) + px;
    int scol = n0 + l15;

    for (int vy = uy - 10; vy <= uy + 10; ++vy) {
        if (vy < 0 || vy >= H2) continue;
        int i  = vy - uy + 10;
        int y2 = 2 * vy + py;
        __syncthreads();
        stage_issue(st, f2base + (size_t)y2 * NW, xp, cg);
        stage_commit_lds(st, Blds, xp, cg);
        __syncthreads();

        f32x4 acc = {0.f, 0.f, 0.f, 0.f};
        #pragma unroll
        for (int kk = 0; kk < 8; ++kk) {
            short8 bfrag = *reinterpret_cast<const short8*>(
                reinterpret_cast<const char*>(Blds) + swz_off(brow, kk * 32 + kgr));
            acc = __builtin_amdgcn_mfma_f32_16x16x32_bf16(afrag[kk], bfrag, acc, 0, 0, 0);
        }
        #pragma unroll
        for (int r = 0; r < 4; ++r)
            Slds[srow + 2 * r][scol] = acc[r] * (1.f / 256.f);
        __syncthreads();

        for (int t = tid; t < ND * 64; t += 512) {
            int j = t >> 6, x = t & 63;
            int vx = (x >> 1) + j - 10;
            float v = ((unsigned)vx < 32u) ? Slds[x][vx] : 0.f;
            outb[(size_t)(i * ND + j) * HW + x] = v;
        }
    }
}

extern "C" void kernel_launch(void* const* d_in, const int* in_sizes, int n_in,
                              void* d_out, int out_size, void* d_ws, size_t ws_size,
                              hipStream_t stream) {
    const float* in1 = (const float*)d_in[0];
    const float* in2 = (const float*)d_in[1];
    float* o = (float*)d_out;
    if (ws_size >= WS_FULL) {
        hipLaunchKernelGGL(prep_kernel, dim3(768), dim3(512), 0, stream, in1, in2, (unsigned short*)d_ws);
        hipLaunchKernelGGL(corr_main4, dim3(768), dim3(512), 0, stream,
                           (const unsigned short*)d_ws, o);
    } else if (ws_size >= WS_F2) {
        hipLaunchKernelGGL(prep_kernel, dim3(384), dim3(512), 0, stream, in1, in2, (unsigned short*)d_ws);
        hipLaunchKernelGGL(corr_main3f, dim3(768), dim3(512), 0, stream,
                           in1, (const unsigned short*)d_ws, o);
    } else {
        hipLaunchKernelGGL(corr_fallback, dim3(384), dim3(512), 0, stream, in1, in2, o);
    }
}

// Round 10
// 45.441 us; speedup vs baseline: 1.5734x; 1.0542x over previous
//
#include <hip/hip_runtime.h>

using short8 = __attribute__((ext_vector_type(8))) short;
using f32x4  = __attribute__((ext_vector_type(4))) float;
using u32x4  = __attribute__((ext_vector_type(4))) unsigned int;

#define NC 256
#define NW 64
#define ND 21
#define HW 3072              /* 48*64, per-channel stride in floats */
#define H2 24

static const size_t WS_FULL = (size_t)768 * 32 * 1024;   /* f2 + f1 blobs */

__device__ __forceinline__ int imax(int a, int b) { return a > b ? a : b; }
__device__ __forceinline__ int imin(int a, int b) { return a < b ? a : b; }

__device__ __forceinline__ unsigned int cvtpk(float a, float b) {
    unsigned int r;
    asm("v_cvt_pk_bf16_f32 %0, %1, %2" : "=v"(r) : "v"(a), "v"(b));
    return r;
}

// barrier draining LDS ops only — global loads/stores stay in flight
#define BARRIER() asm volatile("s_waitcnt lgkmcnt(0)\n\ts_barrier" ::: "memory")

// ============================================================================
// FRAGMENT-ORDERED blobs (32 KB per (src,b,y) row).
// 16B chunk index I = ((kk*2+px)*2+half)*64 + g4*16 + l15   (I in [0,2048))
// holds row x = 2*(half*16+l15)+px, channels c = kk*32+g4*8 .. +7 (consecutive
// shorts = consecutive channels, same 16B content as the old swizzled layout).
// A wave (px,half) reads fragment kk at [base + px*2048 + half*1024 + kk*4096
// + lane*16] -> perfectly coalesced 1 KB per instruction (the R8/R9 direct
// loads were 16-line scattered -> 2-4x L2 amplification, the measured limit).
// ============================================================================

// ---- pre-pass: f32 [c][x] row -> fragment-ordered bf16 blob ----
// XCD-aligned: blob (b*48+y) produced on XCD b (bid%8==b), same as consumers.
// grid 768: blobs 0..383 = f2, 384..767 = f1.
__global__ __launch_bounds__(512, 4) void prep_kernel(const float* __restrict__ f1,
                                                      const float* __restrict__ f2,
                                                      unsigned short* __restrict__ ws) {
    int bid = blockIdx.x;
    int xcd = bid & 7;
    int m   = bid >> 3;            // [0,96)
    const float* src;
    int rid, blob_id;
    if (m < 48) { rid = xcd * 48 + m;        blob_id = rid;       src = f2; }
    else        { rid = xcd * 48 + (m - 48); blob_id = 384 + rid; src = f1; }
    int b = rid / 48, y = rid - b * 48;
    const float* img = src + (size_t)b * NC * HW + (size_t)y * NW;   // + c*HW + x
    char* blob = reinterpret_cast<char*>(ws + ((size_t)blob_id << 14));

    int t = threadIdx.x;
    #pragma unroll
    for (int k = 0; k < 4; ++k) {
        int I    = t + k * 512;
        int lane = I & 63;
        int wv   = I >> 6;             // (kk*2+px)*2 + half
        int l15 = lane & 15, g4 = lane >> 4;
        int half = wv & 1, px = (wv >> 1) & 1, kk = wv >> 2;
        int x  = 2 * (half * 16 + l15) + px;
        int c0 = kk * 32 + g4 * 8;
        const float* p = img + (size_t)c0 * HW + x;
        u32x4 q;
        #pragma unroll
        for (int e = 0; e < 4; ++e) {
            float a  = p[(size_t)(2 * e) * HW];
            float bb = p[(size_t)(2 * e + 1) * HW];
            q[e] = cvtpk(a, bb);       // lo = even channel, hi = odd (verified order)
        }
        *reinterpret_cast<u32x4*>(blob + (size_t)I * 16) = q;   // coalesced 16B/lane
    }
}

// ---- main kernel v5: coalesced direct fragments + reg-double-buffered B ----
// Per iter: MFMA(cur buf) -> issue loads 2 iters ahead -> S to Sl[phase] ->
// BARRIER -> gather.  One barrier/iter; load slack = a full iteration.
__global__ __launch_bounds__(512, 4) void corr_main5(const unsigned short* __restrict__ ws,
                                                     float* __restrict__ out) {
    __shared__ float Sl[2][64 * 32];                      // 2 x 8 KB, additive-swizzled

    int bid = blockIdx.x;
    // bijective XCD swizzle: 768 = 8*96; XCD k serves batch b=k only
    int swz = (bid & 7) * 96 + (bid >> 3);
    int hf  = swz & 1;
    int uy  = (swz >> 1) % 24;
    int g   = swz / 48;            // b*2 + py
    int py  = g & 1, b = g >> 1;
    int y   = 2 * uy + py;

    int tid = threadIdx.x, lane = tid & 63, w = tid >> 6;
    int px = w & 1, mh = (w >> 1) & 1, nh = (w >> 2) & 1;
    int l15 = lane & 15, g4 = lane >> 4;

    float* outb = out + (size_t)b * 441 * HW + (size_t)y * NW;   // + d*HW + x

    int ilo_h = hf ? 11 : 0, ihi_h = hf ? 20 : 10;
    int ilo   = imax(ilo_h, 10 - uy);
    int ihi   = imin(ihi_h, 33 - uy);

    // zero-fill output rows whose displaced source row is out of bounds
    for (int i = ilo_h; i <= ihi_h; ++i) {
        if (i >= ilo && i <= ihi) continue;
        for (int t = tid; t < ND * 64; t += 512) {
            int j = t >> 6, x = t & 63;
            outb[(size_t)(i * ND + j) * HW + x] = 0.f;
        }
    }
    if (ilo > ihi) return;

    // ---- A fragments: coalesced, one-time ----
    const char* ablob = reinterpret_cast<const char*>(ws + ((size_t)(384 + b * 48 + y) << 14));
    int aoff = px * 2048 + mh * 1024 + lane * 16;
    short8 afrag[8];
    #pragma unroll
    for (int kk = 0; kk < 8; ++kk)
        afrag[kk] = *reinterpret_cast<const short8*>(ablob + kk * 4096 + aoff);

    int boff = px * 2048 + nh * 1024 + lane * 16;
    auto loadB = [&](short8* bf, int i) {
        const char* bb = reinterpret_cast<const char*>(
            ws + ((size_t)(b * 48 + 2 * (uy + i - 10) + py) << 14));
        #pragma unroll
        for (int kk = 0; kk < 8; ++kk)
            bf[kk] = *reinterpret_cast<const short8*>(bb + kk * 4096 + boff);
    };

    int srow = 2 * (mh * 16 + g4 * 4) + px;      // + 2*rr
    int scol = nh * 16 + l15;
    int x  = tid & 63;
    int j0 = tid >> 6;                            // j slots: j0, j0+8, j0+16

    short8 bfA[8], bfB[8];
    loadB(bfA, ilo);
    if (ilo + 1 <= ihi) loadB(bfB, ilo + 1);

    int i = ilo;
    while (true) {
        { // ---- phase A: bfA, Sl[0] ----
            f32x4 acc = {0.f, 0.f, 0.f, 0.f};
            #pragma unroll
            for (int kk = 0; kk < 8; ++kk)
                acc = __builtin_amdgcn_mfma_f32_16x16x32_bf16(afrag[kk], bfA[kk], acc, 0, 0, 0);
            if (i + 2 <= ihi) loadB(bfA, i + 2);   // full iteration of slack
            // C/D: col=lane&15 -> vx, row=g4*4+rr -> ux (verified R1-R9)
            // S swizzle: idx = row*32 + ((col+row)&31) -> 2-way (free) both sides
            #pragma unroll
            for (int rr = 0; rr < 4; ++rr) {
                int row = srow + 2 * rr;
                Sl[0][(row << 5) | ((scol + row) & 31)] = acc[rr] * (1.f / 256.f);
            }
            BARRIER();                             // S ready; prev gathers retired
            float* oi = outb + (size_t)i * (ND * HW);
            #pragma unroll
            for (int s = 0; s < 3; ++s) {
                int j = j0 + 8 * s;
                if (j < ND) {
                    int vx = (x >> 1) + j - 10;
                    float v = ((unsigned)vx < 32u) ? Sl[0][(x << 5) | ((vx + x) & 31)] : 0.f;
                    oi[(size_t)j * HW + x] = v;
                }
            }
            if (++i > ihi) break;
        }
        { // ---- phase B: bfB, Sl[1] ----
            f32x4 acc = {0.f, 0.f, 0.f, 0.f};
            #pragma unroll
            for (int kk = 0; kk < 8; ++kk)
                acc = __builtin_amdgcn_mfma_f32_16x16x32_bf16(afrag[kk], bfB[kk], acc, 0, 0, 0);
            if (i + 2 <= ihi) loadB(bfB, i + 2);
            #pragma unroll
            for (int rr = 0; rr < 4; ++rr) {
                int row = srow + 2 * rr;
                Sl[1][(row << 5) | ((scol + row) & 31)] = acc[rr] * (1.f / 256.f);
            }
            BARRIER();
            float* oi = outb + (size_t)i * (ND * HW);
            #pragma unroll
            for (int s = 0; s < 3; ++s) {
                int j = j0 + 8 * s;
                if (j < ND) {
                    int vx = (x >> 1) + j - 10;
                    float v = ((unsigned)vx < 32u) ? Sl[1][(x << 5) | ((vx + x) & 31)] : 0.f;
                    oi[(size_t)j * HW + x] = v;
                }
            }
            if (++i > ihi) break;
        }
    }
}

// ============================================================================
// fallback (round-1 structure, known good, no workspace) — old swizzled-LDS
// staging helpers kept only for this path.
// ============================================================================
__device__ __forceinline__ unsigned int swz_off(int row, int cb) {
    return (row << 9) + ((cb << 1) ^ (((row >> 1) & 7) << 4));
}

struct Stage { float2 v[16]; };

__device__ __forceinline__ void stage_issue(Stage& st, const float* rowbase, int xp, int cg) {
    const float* s = rowbase + 2 * xp;
    #pragma unroll
    for (int cc = 0; cc < 2; ++cc)
        #pragma unroll
        for (int e = 0; e < 4; ++e) {
            int c = cc * 128 + cg * 8 + 2 * e;
            st.v[cc * 8 + 2 * e    ] = *reinterpret_cast<const float2*>(s + (size_t)c * HW);
            st.v[cc * 8 + 2 * e + 1] = *reinterpret_cast<const float2*>(s + (size_t)(c + 1) * HW);
        }
}

__device__ __forceinline__ void stage_commit_lds(const Stage& st, unsigned short* lds, int xp, int cg) {
    #pragma unroll
    for (int cc = 0; cc < 2; ++cc) {
        int c0 = cc * 128 + cg * 8;
        u32x4 p0, p1;
        #pragma unroll
        for (int e = 0; e < 4; ++e) {
            float2 va = st.v[cc * 8 + 2 * e];
            float2 vb = st.v[cc * 8 + 2 * e + 1];
            p0[e] = cvtpk(va.x, vb.x);
            p1[e] = cvtpk(va.y, vb.y);
        }
        *reinterpret_cast<u32x4*>(reinterpret_cast<char*>(lds) + swz_off(2 * xp,     c0)) = p0;
        *reinterpret_cast<u32x4*>(reinterpret_cast<char*>(lds) + swz_off(2 * xp + 1, c0)) = p1;
    }
}

__global__ __launch_bounds__(512, 4) void corr_fallback(const float* __restrict__ f1,
                                                        const float* __restrict__ f2,
                                                        float* __restrict__ out) {
    __shared__ __align__(16) unsigned short Alds[64 * 256];
    __shared__ __align__(16) unsigned short Blds[64 * 256];
    __shared__ float Slds[64][33];

    int bid = blockIdx.x;
    int swz = (bid & 7) * 48 + (bid >> 3);
    int uy = swz % 24;
    int g  = swz / 24;
    int py = g & 1;
    int b  = g >> 1;
    int y  = 2 * uy + py;

    int tid = threadIdx.x, lane = tid & 63, w = tid >> 6;
    int xp = tid & 31, cg = tid >> 5;

    const float* f1row  = f1 + (size_t)b * NC * HW + (size_t)y * NW;
    const float* f2base = f2 + (size_t)b * NC * HW;
    float* outb = out + (size_t)b * 441 * HW + (size_t)y * NW;

    for (int i = 0; i < ND; ++i) {
        int vy = uy + i - 10;
        if (vy >= 0 && vy < H2) continue;
        for (int t = tid; t < ND * 64; t += 512) {
            int j = t >> 6, x = t & 63;
            outb[(size_t)(i * ND + j) * HW + x] = 0.f;
        }
    }

    Stage st;
    stage_issue(st, f1row, xp, cg);
    stage_commit_lds(st, Alds, xp, cg);
    __syncthreads();

    int px  = w & 1;
    int m0  = ((w >> 1) & 1) * 16;
    int n0  = ((w >> 2) & 1) * 16;
    int l15 = lane & 15;
    int kgr = (lane >> 4) * 8;

    short8 afrag[8];
    int arow = 2 * (m0 + l15) + px;
    #pragma unroll
    for (int kk = 0; kk < 8; ++kk)
        afrag[kk] = *reinterpret_cast<const short8*>(
            reinterpret_cast<const char*>(Alds) + swz_off(arow, kk * 32 + kgr));

    int brow = 2 * (n0 + l15) + px;
    int srow = 2 * (m0 + (lane >> 4) * 4) + px;
    int scol = n0 + l15;

    for (int vy = uy - 10; vy <= uy + 10; ++vy) {
        if (vy < 0 || vy >= H2) continue;
        int i  = vy - uy + 10;
        int y2 = 2 * vy + py;
        __syncthreads();
        stage_issue(st, f2base + (size_t)y2 * NW, xp, cg);
        stage_commit_lds(st, Blds, xp, cg);
        __syncthreads();

        f32x4 acc = {0.f, 0.f, 0.f, 0.f};
        #pragma unroll
        for (int kk = 0; kk < 8; ++kk) {
            short8 bfrag = *reinterpret_cast<const short8*>(
                reinterpret_cast<const char*>(Blds) + swz_off(brow, kk * 32 + kgr));
            acc = __builtin_amdgcn_mfma_f32_16x16x32_bf16(afrag[kk], bfrag, acc, 0, 0, 0);
        }
        #pragma unroll
        for (int r = 0; r < 4; ++r)
            Slds[srow + 2 * r][scol] = acc[r] * (1.f / 256.f);
        __syncthreads();

        for (int t = tid; t < ND * 64; t += 512) {
            int j = t >> 6, x = t & 63;
            int vx = (x >> 1) + j - 10;
            float v = ((unsigned)vx < 32u) ? Slds[x][vx] : 0.f;
            outb[(size_t)(i * ND + j) * HW + x] = v;
        }
    }
}

extern "C" void kernel_launch(void* const* d_in, const int* in_sizes, int n_in,
                              void* d_out, int out_size, void* d_ws, size_t ws_size,
                              hipStream_t stream) {
    const float* in1 = (const float*)d_in[0];
    const float* in2 = (const float*)d_in[1];
    float* o = (float*)d_out;
    if (ws_size >= WS_FULL) {
        hipLaunchKernelGGL(prep_kernel, dim3(768), dim3(512), 0, stream, in1, in2, (unsigned short*)d_ws);
        hipLaunchKernelGGL(corr_main5, dim3(768), dim3(512), 0, stream,
                           (const unsigned short*)d_ws, o);
    } else {
        hipLaunchKernelGGL(corr_fallback, dim3(384), dim3(512), 0, stream, in1, in2, o);
    }
}

// Round 11
// 44.954 us; speedup vs baseline: 1.5904x; 1.0108x over previous
//
#include <hip/hip_runtime.h>

using short8 = __attribute__((ext_vector_type(8))) short;
using f32x4  = __attribute__((ext_vector_type(4))) float;
using u32x4  = __attribute__((ext_vector_type(4))) unsigned int;

#define NC 256
#define NW 64
#define ND 21
#define HW 3072              /* 48*64, per-channel stride in floats */
#define H2 24

static const size_t WS_FULL = (size_t)768 * 32 * 1024;   /* f2 + f1 blobs */

__device__ __forceinline__ int imax(int a, int b) { return a > b ? a : b; }
__device__ __forceinline__ int imin(int a, int b) { return a < b ? a : b; }

__device__ __forceinline__ unsigned int cvtpk(float a, float b) {
    unsigned int r;
    asm("v_cvt_pk_bf16_f32 %0, %1, %2" : "=v"(r) : "v"(a), "v"(b));
    return r;
}

// barrier draining LDS ops only — global loads/stores stay in flight
#define BARRIER() asm volatile("s_waitcnt lgkmcnt(0)\n\ts_barrier" ::: "memory")

// ============================================================================
// FRAGMENT-ORDERED blobs (32 KB per (src,b,y) row).
// 16B chunk I = ((kk*2+px)*2+half)*64 + g4*16 + l15 holds row
// x = 2*(half*16+l15)+px, channels c = kk*32+g4*8 .. +7 (lo=even, hi=odd).
// Reader (main5): frag kk at [blob + kk*4096 + px*2048 + half*1024 + lane*16]
// -> perfectly coalesced 1 KB per wave-instruction.
// ============================================================================

struct Stage { float2 v[16]; };   // one f32 row slice: 128 B/thread

// verified R1-R10: lane = xp -> consecutive float2 -> 256 B contiguous per row
__device__ __forceinline__ void stage_issue(Stage& st, const float* rowbase, int xp, int cg) {
    const float* s = rowbase + 2 * xp;
    #pragma unroll
    for (int cc = 0; cc < 2; ++cc)
        #pragma unroll
        for (int e = 0; e < 4; ++e) {
            int c = cc * 128 + cg * 8 + 2 * e;
            st.v[cc * 8 + 2 * e    ] = *reinterpret_cast<const float2*>(s + (size_t)c * HW);
            st.v[cc * 8 + 2 * e + 1] = *reinterpret_cast<const float2*>(s + (size_t)(c + 1) * HW);
        }
}

__device__ __forceinline__ void stage_pack(const Stage& st, int cc, u32x4& p0, u32x4& p1) {
    #pragma unroll
    for (int e = 0; e < 4; ++e) {
        float2 va = st.v[cc * 8 + 2 * e];       // channel c0+2e   @ (x0, x1)
        float2 vb = st.v[cc * 8 + 2 * e + 1];   // channel c0+2e+1 @ (x0, x1)
        p0[e] = cvtpk(va.x, vb.x);              // x0: lo=even ch, hi=odd ch
        p1[e] = cvtpk(va.y, vb.y);              // x1
    }
}

// ---- pre-pass: coalesced f32 reads -> fragment-ordered bf16 blob writes ----
// XCD-aligned: blob (b*48+y) produced on XCD b (bid%8==b), same as consumers.
// grid 768: blobs 0..383 = f2, 384..767 = f1.
__global__ __launch_bounds__(512, 4) void prep_kernel(const float* __restrict__ f1,
                                                      const float* __restrict__ f2,
                                                      unsigned short* __restrict__ ws) {
    int bid = blockIdx.x;
    int xcd = bid & 7;
    int m   = bid >> 3;            // [0,96)
    const float* src;
    int rid, blob_id;
    if (m < 48) { rid = xcd * 48 + m;        blob_id = rid;       src = f2; }
    else        { rid = xcd * 48 + (m - 48); blob_id = 384 + rid; src = f1; }
    int b = rid / 48, y = rid - b * 48;
    const float* row = src + (size_t)b * NC * HW + (size_t)y * NW;
    char* blob = reinterpret_cast<char*>(ws + ((size_t)blob_id << 14));

    int tid = threadIdx.x, xp = tid & 31, cg = tid >> 5;
    int half = xp >> 4, l15 = xp & 15, g4 = cg & 3;

    Stage st;
    stage_issue(st, row, xp, cg);   // x0 = 2*xp (px=0), x1 = 2*xp+1 (px=1)

    #pragma unroll
    for (int cc = 0; cc < 2; ++cc) {
        u32x4 p0, p1;
        stage_pack(st, cc, p0, p1);
        int kk = cc * 4 + (cg >> 2);
        // byte = kk*4096 + px*2048 + half*1024 + g4*256 + l15*16
        char* base = blob + kk * 4096 + half * 1024 + g4 * 256 + l15 * 16;
        *reinterpret_cast<u32x4*>(base)        = p0;   // px = 0
        *reinterpret_cast<u32x4*>(base + 2048) = p1;   // px = 1
    }
}

// ---- main kernel v5 (IDENTICAL to R10): coalesced direct fragments ----
__global__ __launch_bounds__(512, 4) void corr_main5(const unsigned short* __restrict__ ws,
                                                     float* __restrict__ out) {
    __shared__ float Sl[2][64 * 32];                      // 2 x 8 KB, additive-swizzled

    int bid = blockIdx.x;
    // bijective XCD swizzle: 768 = 8*96; XCD k serves batch b=k only
    int swz = (bid & 7) * 96 + (bid >> 3);
    int hf  = swz & 1;
    int uy  = (swz >> 1) % 24;
    int g   = swz / 48;            // b*2 + py
    int py  = g & 1, b = g >> 1;
    int y   = 2 * uy + py;

    int tid = threadIdx.x, lane = tid & 63, w = tid >> 6;
    int px = w & 1, mh = (w >> 1) & 1, nh = (w >> 2) & 1;
    int l15 = lane & 15, g4 = lane >> 4;

    float* outb = out + (size_t)b * 441 * HW + (size_t)y * NW;   // + d*HW + x

    int ilo_h = hf ? 11 : 0, ihi_h = hf ? 20 : 10;
    int ilo   = imax(ilo_h, 10 - uy);
    int ihi   = imin(ihi_h, 33 - uy);

    // zero-fill output rows whose displaced source row is out of bounds
    for (int i = ilo_h; i <= ihi_h; ++i) {
        if (i >= ilo && i <= ihi) continue;
        for (int t = tid; t < ND * 64; t += 512) {
            int j = t >> 6, x = t & 63;
            outb[(size_t)(i * ND + j) * HW + x] = 0.f;
        }
    }
    if (ilo > ihi) return;

    // ---- A fragments: coalesced, one-time ----
    const char* ablob = reinterpret_cast<const char*>(ws + ((size_t)(384 + b * 48 + y) << 14));
    int aoff = px * 2048 + mh * 1024 + lane * 16;
    short8 afrag[8];
    #pragma unroll
    for (int kk = 0; kk < 8; ++kk)
        afrag[kk] = *reinterpret_cast<const short8*>(ablob + kk * 4096 + aoff);

    int boff = px * 2048 + nh * 1024 + lane * 16;
    auto loadB = [&](short8* bf, int i) {
        const char* bb = reinterpret_cast<const char*>(
            ws + ((size_t)(b * 48 + 2 * (uy + i - 10) + py) << 14));
        #pragma unroll
        for (int kk = 0; kk < 8; ++kk)
            bf[kk] = *reinterpret_cast<const short8*>(bb + kk * 4096 + boff);
    };

    int srow = 2 * (mh * 16 + g4 * 4) + px;      // + 2*rr
    int scol = nh * 16 + l15;
    int x  = tid & 63;
    int j0 = tid >> 6;                            // j slots: j0, j0+8, j0+16

    short8 bfA[8], bfB[8];
    loadB(bfA, ilo);
    if (ilo + 1 <= ihi) loadB(bfB, ilo + 1);

    int i = ilo;
    while (true) {
        { // ---- phase A: bfA, Sl[0] ----
            f32x4 acc = {0.f, 0.f, 0.f, 0.f};
            #pragma unroll
            for (int kk = 0; kk < 8; ++kk)
                acc = __builtin_amdgcn_mfma_f32_16x16x32_bf16(afrag[kk], bfA[kk], acc, 0, 0, 0);
            if (i + 2 <= ihi) loadB(bfA, i + 2);   // full iteration of slack
            // C/D: col=lane&15 -> vx, row=g4*4+rr -> ux (verified R1-R10)
            // S swizzle: idx = row*32 + ((col+row)&31) -> 2-way (free) both sides
            #pragma unroll
            for (int rr = 0; rr < 4; ++rr) {
                int row = srow + 2 * rr;
                Sl[0][(row << 5) | ((scol + row) & 31)] = acc[rr] * (1.f / 256.f);
            }
            BARRIER();                             // S ready; prev gathers retired
            float* oi = outb + (size_t)i * (ND * HW);
            #pragma unroll
            for (int s = 0; s < 3; ++s) {
                int j = j0 + 8 * s;
                if (j < ND) {
                    int vx = (x >> 1) + j - 10;
                    float v = ((unsigned)vx < 32u) ? Sl[0][(x << 5) | ((vx + x) & 31)] : 0.f;
                    oi[(size_t)j * HW + x] = v;
                }
            }
            if (++i > ihi) break;
        }
        { // ---- phase B: bfB, Sl[1] ----
            f32x4 acc = {0.f, 0.f, 0.f, 0.f};
            #pragma unroll
            for (int kk = 0; kk < 8; ++kk)
                acc = __builtin_amdgcn_mfma_f32_16x16x32_bf16(afrag[kk], bfB[kk], acc, 0, 0, 0);
            if (i + 2 <= ihi) loadB(bfB, i + 2);
            #pragma unroll
            for (int rr = 0; rr < 4; ++rr) {
                int row = srow + 2 * rr;
                Sl[1][(row << 5) | ((scol + row) & 31)] = acc[rr] * (1.f / 256.f);
            }
            BARRIER();
            float* oi = outb + (size_t)i * (ND * HW);
            #pragma unroll
            for (int s = 0; s < 3; ++s) {
                int j = j0 + 8 * s;
                if (j < ND) {
                    int vx = (x >> 1) + j - 10;
                    float v = ((unsigned)vx < 32u) ? Sl[1][(x << 5) | ((vx + x) & 31)] : 0.f;
                    oi[(size_t)j * HW + x] = v;
                }
            }
            if (++i > ihi) break;
        }
    }
}

// ============================================================================
// fallback (round-1 structure, known good, no workspace)
// ============================================================================
__device__ __forceinline__ unsigned int swz_off(int row, int cb) {
    return (row << 9) + ((cb << 1) ^ (((row >> 1) & 7) << 4));
}

__device__ __forceinline__ void stage_commit_lds(const Stage& st, unsigned short* lds, int xp, int cg) {
    #pragma unroll
    for (int cc = 0; cc < 2; ++cc) {
        int c0 = cc * 128 + cg * 8;
        u32x4 p0, p1;
        stage_pack(st, cc, p0, p1);
        *reinterpret_cast<u32x4*>(reinterpret_cast<char*>(lds) + swz_off(2 * xp,     c0)) = p0;
        *reinterpret_cast<u32x4*>(reinterpret_cast<char*>(lds) + swz_off(2 * xp + 1, c0)) = p1;
    }
}

__global__ __launch_bounds__(512, 4) void corr_fallback(const float* __restrict__ f1,
                                                        const float* __restrict__ f2,
                                                        float* __restrict__ out) {
    __shared__ __align__(16) unsigned short Alds[64 * 256];
    __shared__ __align__(16) unsigned short Blds[64 * 256];
    __shared__ float Slds[64][33];

    int bid = blockIdx.x;
    int swz = (bid & 7) * 48 + (bid >> 3);
    int uy = swz % 24;
    int g  = swz / 24;
    int py = g & 1;
    int b  = g >> 1;
    int y  = 2 * uy + py;

    int tid = threadIdx.x, lane = tid & 63, w = tid >> 6;
    int xp = tid & 31, cg = tid >> 5;

    const float* f1row  = f1 + (size_t)b * NC * HW + (size_t)y * NW;
    const float* f2base = f2 + (size_t)b * NC * HW;
    float* outb = out + (size_t)b * 441 * HW + (size_t)y * NW;

    for (int i = 0; i < ND; ++i) {
        int vy = uy + i - 10;
        if (vy >= 0 && vy < H2) continue;
        for (int t = tid; t < ND * 64; t += 512) {
            int j = t >> 6, x = t & 63;
            outb[(size_t)(i * ND + j) * HW + x] = 0.f;
        }
    }

    Stage st;
    stage_issue(st, f1row, xp, cg);
    stage_commit_lds(st, Alds, xp, cg);
    __syncthreads();

    int px  = w & 1;
    int m0  = ((w >> 1) & 1) * 16;
    int n0  = ((w >> 2) & 1) * 16;
    int l15 = lane & 15;
    int kgr = (lane >> 4) * 8;

    short8 afrag[8];
    int arow = 2 * (m0 + l15) + px;
    #pragma unroll
    for (int kk = 0; kk < 8; ++kk)
        afrag[kk] = *reinterpret_cast<const short8*>(
            reinterpret_cast<const char*>(Alds) + swz_off(arow, kk * 32 + kgr));

    int brow = 2 * (n0 + l15) + px;
    int srow = 2 * (m0 + (lane >> 4) * 4) + px;
    int scol = n0 + l15;

    for (int vy = uy - 10; vy <= uy + 10; ++vy) {
        if (vy < 0 || vy >= H2) continue;
        int i  = vy - uy + 10;
        int y2 = 2 * vy + py;
        __syncthreads();
        stage_issue(st, f2base + (size_t)y2 * NW, xp, cg);
        stage_commit_lds(st, Blds, xp, cg);
        __syncthreads();

        f32x4 acc = {0.f, 0.f, 0.f, 0.f};
        #pragma unroll
        for (int kk = 0; kk < 8; ++kk) {
            short8 bfrag = *reinterpret_cast<const short8*>(
                reinterpret_cast<const char*>(Blds) + swz_off(brow, kk * 32 + kgr));
            acc = __builtin_amdgcn_mfma_f32_16x16x32_bf16(afrag[kk], bfrag, acc, 0, 0, 0);
        }
        #pragma unroll
        for (int r = 0; r < 4; ++r)
            Slds[srow + 2 * r][scol] = acc[r] * (1.f / 256.f);
        __syncthreads();

        for (int t = tid; t < ND * 64; t += 512) {
            int j = t >> 6, x = t & 63;
            int vx = (x >> 1) + j - 10;
            float v = ((unsigned)vx < 32u) ? Slds[x][vx] : 0.f;
            outb[(size_t)(i * ND + j) * HW + x] = v;
        }
    }
}

extern "C" void kernel_launch(void* const* d_in, const int* in_sizes, int n_in,
                              void* d_out, int out_size, void* d_ws, size_t ws_size,
                              hipStream_t stream) {
    const float* in1 = (const float*)d_in[0];
    const float* in2 = (const float*)d_in[1];
    float* o = (float*)d_out;
    if (ws_size >= WS_FULL) {
        hipLaunchKernelGGL(prep_kernel, dim3(768), dim3(512), 0, stream, in1, in2, (unsigned short*)d_ws);
        hipLaunchKernelGGL(corr_main5, dim3(768), dim3(512), 0, stream,
                           (const unsigned short*)d_ws, o);
    } else {
        hipLaunchKernelGGL(corr_fallback, dim3(384), dim3(512), 0, stream, in1, in2, o);
    }
}